// Round 1
// baseline (850.835 us; speedup 1.0000x reference)
//
#include <hip/hip_runtime.h>

#define NUM_N 50000
#define NUM_E 20000
#define IN_DIM 256
#define OUT_DIM 128

// ---------------- histogram: node & edge degrees ----------------
__global__ void hist_kernel(const int* __restrict__ node_idx,
                            const int* __restrict__ edge_idx, int nnz,
                            int* __restrict__ cnt_n, int* __restrict__ cnt_e) {
    int i = blockIdx.x * blockDim.x + threadIdx.x;
    int stride = gridDim.x * blockDim.x;
    for (; i < nnz; i += stride) {
        atomicAdd(&cnt_n[node_idx[i]], 1);
        atomicAdd(&cnt_e[edge_idx[i]], 1);
    }
}

// ---------------- single-block exclusive scan -> row_ptr ----------------
__global__ void scan_kernel(const int* __restrict__ cnt, int* __restrict__ rp, int n) {
    __shared__ int sums[1024];
    int t = threadIdx.x;
    int C = (n + 1023) / 1024;
    int beg = t * C;
    int end = min(beg + C, n);
    int s = 0;
    for (int i = beg; i < end; ++i) s += cnt[i];
    sums[t] = s;
    __syncthreads();
    // Hillis-Steele inclusive scan
    for (int off = 1; off < 1024; off <<= 1) {
        int v = (t >= off) ? sums[t - off] : 0;
        __syncthreads();
        sums[t] += v;
        __syncthreads();
    }
    int run = (t == 0) ? 0 : sums[t - 1];   // exclusive prefix
    for (int i = beg; i < end; ++i) { rp[i] = run; run += cnt[i]; }
    if (t == 1023) rp[n] = run;             // total
}

// ---------------- fill CSR adjacency lists ----------------
__global__ void fill_kernel(const int* __restrict__ node_idx,
                            const int* __restrict__ edge_idx, int nnz,
                            int* __restrict__ cur_n, int* __restrict__ cur_e,
                            int* __restrict__ col_n, int* __restrict__ col_e) {
    int i = blockIdx.x * blockDim.x + threadIdx.x;
    int stride = gridDim.x * blockDim.x;
    for (; i < nnz; i += stride) {
        int v = node_idx[i];
        int e = edge_idx[i];
        int pe = atomicAdd(&cur_e[e], 1);
        col_e[pe] = v;              // members (nodes) of each hyperedge
        int pn = atomicAdd(&cur_n[v], 1);
        col_n[pn] = e;              // hyperedges incident to each node
    }
}

// ---------------- xw = x @ W  (fp32, BM=64 BN=128 BK=32, 4x8/thread) ----------------
__global__ __launch_bounds__(256) void gemm_kernel(const float* __restrict__ x,
                                                   const float* __restrict__ w,
                                                   float* __restrict__ xw, int nrows) {
    __shared__ float As[64][33];    // [row][k] padded
    __shared__ float Ws[32][128];   // [k][col]
    int tid = threadIdx.x;
    int block_row = blockIdx.x * 64;
    int rg = tid >> 4;              // 0..15
    int cg = tid & 15;              // 0..15
    int r0 = rg * 4, c0 = cg * 8;
    float acc[4][8] = {};
    for (int k0 = 0; k0 < IN_DIM; k0 += 32) {
        // A tile: 64 rows x 32 k = 512 float4; 2 per thread
#pragma unroll
        for (int rep = 0; rep < 2; ++rep) {
            int f = tid + rep * 256;
            int row = f >> 3, kq = f & 7;
            float4 v = make_float4(0.f, 0.f, 0.f, 0.f);
            int grow = block_row + row;
            if (grow < nrows) v = *(const float4*)&x[(size_t)grow * IN_DIM + k0 + kq * 4];
            As[row][kq * 4 + 0] = v.x;
            As[row][kq * 4 + 1] = v.y;
            As[row][kq * 4 + 2] = v.z;
            As[row][kq * 4 + 3] = v.w;
        }
        // W tile: 32 k x 128 cols = 1024 float4; 4 per thread
#pragma unroll
        for (int rep = 0; rep < 4; ++rep) {
            int f = tid + rep * 256;
            int kk = f >> 5, cq = f & 31;
            float4 v = *(const float4*)&w[(size_t)(k0 + kk) * OUT_DIM + cq * 4];
            *(float4*)&Ws[kk][cq * 4] = v;
        }
        __syncthreads();
#pragma unroll
        for (int k = 0; k < 32; ++k) {
            float av[4];
#pragma unroll
            for (int i = 0; i < 4; ++i) av[i] = As[r0 + i][k];
            float4 b0 = *(const float4*)&Ws[k][c0];
            float4 b1 = *(const float4*)&Ws[k][c0 + 4];
            float bv[8] = {b0.x, b0.y, b0.z, b0.w, b1.x, b1.y, b1.z, b1.w};
#pragma unroll
            for (int i = 0; i < 4; ++i)
#pragma unroll
                for (int j = 0; j < 8; ++j)
                    acc[i][j] += av[i] * bv[j];
        }
        __syncthreads();
    }
#pragma unroll
    for (int i = 0; i < 4; ++i) {
        int grow = block_row + r0 + i;
        if (grow < nrows) {
            *(float4*)&xw[(size_t)grow * OUT_DIM + c0] =
                make_float4(acc[i][0], acc[i][1], acc[i][2], acc[i][3]);
            *(float4*)&xw[(size_t)grow * OUT_DIM + c0 + 4] =
                make_float4(acc[i][4], acc[i][5], acc[i][6], acc[i][7]);
        }
    }
}

// ---------------- node -> hyperedge aggregation (one wave per edge) ----------------
__global__ __launch_bounds__(256) void edge_agg_kernel(const float* __restrict__ xw,
                                                       const int* __restrict__ rp_e,
                                                       const int* __restrict__ col_e,
                                                       float* __restrict__ m_e) {
    int wave = blockIdx.x * 4 + (threadIdx.x >> 6);
    int lane = threadIdx.x & 63;
    if (wave >= NUM_E) return;
    int beg = rp_e[wave], end = rp_e[wave + 1];
    float2 a0 = make_float2(0.f, 0.f), a1 = make_float2(0.f, 0.f);
    int j = beg;
    for (; j + 2 <= end; j += 2) {
        int n0 = col_e[j], n1 = col_e[j + 1];
        float2 v0 = *(const float2*)&xw[(size_t)n0 * OUT_DIM + lane * 2];
        float2 v1 = *(const float2*)&xw[(size_t)n1 * OUT_DIM + lane * 2];
        a0.x += v0.x; a0.y += v0.y;
        a1.x += v1.x; a1.y += v1.y;
    }
    if (j < end) {
        int n0 = col_e[j];
        float2 v0 = *(const float2*)&xw[(size_t)n0 * OUT_DIM + lane * 2];
        a0.x += v0.x; a0.y += v0.y;
    }
    float binv = (end > beg) ? 1.0f / (float)(end - beg) : 0.0f;
    float2 r = make_float2((a0.x + a1.x) * binv, (a0.y + a1.y) * binv);
    *(float2*)&m_e[(size_t)wave * OUT_DIM + lane * 2] = r;
}

// ---------------- hyperedge -> node + d_inv + bias + relu + mean-pool ----------------
__global__ __launch_bounds__(256) void node_agg_kernel(const float* __restrict__ m_e,
                                                       const int* __restrict__ rp_n,
                                                       const int* __restrict__ col_n,
                                                       const float* __restrict__ bias,
                                                       float* __restrict__ mean_acc) {
    __shared__ float part[128];
    int tid = threadIdx.x;
    if (tid < 128) part[tid] = 0.f;
    __syncthreads();
    int lane = tid & 63;
    int gwave = blockIdx.x * 4 + (tid >> 6);
    int nwaves = gridDim.x * 4;
    float2 b = *(const float2*)&bias[lane * 2];
    float2 macc = make_float2(0.f, 0.f);
    for (int v = gwave; v < NUM_N; v += nwaves) {
        int beg = rp_n[v], end = rp_n[v + 1];
        float2 a0 = make_float2(0.f, 0.f), a1 = make_float2(0.f, 0.f);
        int j = beg;
        for (; j + 2 <= end; j += 2) {
            int e0 = col_n[j], e1 = col_n[j + 1];
            float2 t0 = *(const float2*)&m_e[(size_t)e0 * OUT_DIM + lane * 2];
            float2 t1 = *(const float2*)&m_e[(size_t)e1 * OUT_DIM + lane * 2];
            a0.x += t0.x; a0.y += t0.y;
            a1.x += t1.x; a1.y += t1.y;
        }
        if (j < end) {
            int e0 = col_n[j];
            float2 t0 = *(const float2*)&m_e[(size_t)e0 * OUT_DIM + lane * 2];
            a0.x += t0.x; a0.y += t0.y;
        }
        float dinv = (end > beg) ? 1.0f / (float)(end - beg) : 0.0f;
        float o0 = fmaxf((a0.x + a1.x) * dinv + b.x, 0.f);
        float o1 = fmaxf((a0.y + a1.y) * dinv + b.y, 0.f);
        macc.x += o0; macc.y += o1;
    }
    atomicAdd(&part[lane * 2], macc.x);
    atomicAdd(&part[lane * 2 + 1], macc.y);
    __syncthreads();
    if (tid < 128) atomicAdd(&mean_acc[tid], part[tid]);
}

__global__ void finalize_kernel(const float* __restrict__ mean_acc, float* __restrict__ out) {
    int t = threadIdx.x;
    if (t < 128) out[t] = mean_acc[t] * (1.0f / (float)NUM_N);
}

extern "C" void kernel_launch(void* const* d_in, const int* in_sizes, int n_in,
                              void* d_out, int out_size, void* d_ws, size_t ws_size,
                              hipStream_t stream) {
    const float* x    = (const float*)d_in[0];
    const float* w    = (const float*)d_in[1];
    const float* bias = (const float*)d_in[2];
    const int*   hei  = (const int*)d_in[3];
    int nnz = in_sizes[3] / 2;
    const int* node_idx = hei;        // hyperedge_index[0]
    const int* edge_idx = hei + nnz;  // hyperedge_index[1]
    float* out = (float*)d_out;

    char* ws = (char*)d_ws;
    float* xw   = (float*)(ws);                    // 50000*128*4 = 25,600,000
    float* m_e  = (float*)(ws + 25600000);         // 20000*128*4 = 10,240,000
    int*   col_e = (int*)(ws + 35840000);          // nnz*4 = 6,400,000
    int*   col_n = (int*)(ws + 42240000);          // nnz*4 = 6,400,000
    int*   rp_e  = (int*)(ws + 48640000);          // 20001*4 -> 80,128
    int*   rp_n  = (int*)(ws + 48720128);          // 50001*4 -> 200,192
    int*   cur_e = (int*)(ws + 48920320);          // 20000*4 = 80,000
    int*   cur_n = (int*)(ws + 49000320);          // 50000*4 = 200,000
    int*   cnt_n = (int*)(ws + 49200320);          // 50000*4 = 200,000
    int*   cnt_e = (int*)(ws + 49400320);          // 20000*4 = 80,000
    float* macc  = (float*)(ws + 49480320);        // 128*4   = 512

    // zero counts + mean accumulator (contiguous region)
    hipMemsetAsync(ws + 49200320, 0, 200000 + 80000 + 512, stream);

    hist_kernel<<<2048, 256, 0, stream>>>(node_idx, edge_idx, nnz, cnt_n, cnt_e);
    scan_kernel<<<1, 1024, 0, stream>>>(cnt_e, rp_e, NUM_E);
    scan_kernel<<<1, 1024, 0, stream>>>(cnt_n, rp_n, NUM_N);
    hipMemcpyAsync(cur_e, rp_e, NUM_E * sizeof(int), hipMemcpyDeviceToDevice, stream);
    hipMemcpyAsync(cur_n, rp_n, NUM_N * sizeof(int), hipMemcpyDeviceToDevice, stream);
    fill_kernel<<<2048, 256, 0, stream>>>(node_idx, edge_idx, nnz, cur_n, cur_e, col_n, col_e);

    gemm_kernel<<<(NUM_N + 63) / 64, 256, 0, stream>>>(x, w, xw, NUM_N);

    edge_agg_kernel<<<NUM_E / 4, 256, 0, stream>>>(xw, rp_e, col_e, m_e);
    node_agg_kernel<<<1024, 256, 0, stream>>>(m_e, rp_n, col_n, bias, macc);
    finalize_kernel<<<1, 128, 0, stream>>>(macc, out);
}

// Round 2
// 719.360 us; speedup vs baseline: 1.1828x; 1.1828x over previous
//
#include <hip/hip_runtime.h>

#define NUM_N 50000
#define NUM_E 20000
#define IN_DIM 256
#define OUT_DIM 128
#define NPART 8   // one destination range per XCD (blockIdx % 8 round-robins XCDs)

// ---------------- histogram: node & edge degrees ----------------
__global__ void hist_kernel(const int* __restrict__ node_idx,
                            const int* __restrict__ edge_idx, int nnz,
                            int* __restrict__ cnt_n, int* __restrict__ cnt_e) {
    int i = blockIdx.x * blockDim.x + threadIdx.x;
    int stride = gridDim.x * blockDim.x;
    for (; i < nnz; i += stride) {
        atomicAdd(&cnt_n[node_idx[i]], 1);
        atomicAdd(&cnt_e[edge_idx[i]], 1);
    }
}

// ---------------- dual single-block exclusive scan -> row_ptr + cur ----------------
__global__ void scan_dual_kernel(const int* __restrict__ cnt_e, int* __restrict__ rp_e,
                                 int* __restrict__ cur_e,
                                 const int* __restrict__ cnt_n, int* __restrict__ rp_n,
                                 int* __restrict__ cur_n) {
    const int* cnt; int* rp; int* cur; int n;
    if (blockIdx.x == 0) { cnt = cnt_e; rp = rp_e; cur = cur_e; n = NUM_E; }
    else                 { cnt = cnt_n; rp = rp_n; cur = cur_n; n = NUM_N; }
    __shared__ int sums[1024];
    int t = threadIdx.x;
    int C = (n + 1023) / 1024;
    int beg = t * C;
    int end = min(beg + C, n);
    int s = 0;
    for (int i = beg; i < end; ++i) s += cnt[i];
    sums[t] = s;
    __syncthreads();
    for (int off = 1; off < 1024; off <<= 1) {
        int v = (t >= off) ? sums[t - off] : 0;
        __syncthreads();
        sums[t] += v;
        __syncthreads();
    }
    int run = (t == 0) ? 0 : sums[t - 1];   // exclusive prefix
    for (int i = beg; i < end; ++i) { rp[i] = run; cur[i] = run; run += cnt[i]; }
    if (t == 1023) rp[n] = run;             // total
}

// ---------------- fill CSR adjacency lists, destination-partitioned ----------------
// Partition p (= blockIdx % 8) owns edge range [p*2500, (p+1)*2500) and node
// range [p*6250, (p+1)*6250). Only partition p writes col entries in its
// range, so each cache line of col_e/col_n is written by one XCD and merges
// fully in that XCD's L2 before write-back (kills the 15x write amplification).
__global__ __launch_bounds__(256) void fill_part_kernel(const int* __restrict__ node_idx,
                                                        const int* __restrict__ edge_idx, int nnz,
                                                        int* __restrict__ cur_n, int* __restrict__ cur_e,
                                                        int* __restrict__ col_n, int* __restrict__ col_e) {
    int p = blockIdx.x & (NPART - 1);
    int blk = blockIdx.x >> 3;
    int nblk = gridDim.x >> 3;
    const int E_RANGE = NUM_E / NPART;   // 2500
    const int N_RANGE = NUM_N / NPART;   // 6250
    int e_lo = p * E_RANGE, e_hi = e_lo + E_RANGE;
    int n_lo = p * N_RANGE, n_hi = n_lo + N_RANGE;
    int stride = nblk * blockDim.x;
    for (int i = blk * blockDim.x + threadIdx.x; i < nnz; i += stride) {
        int v = node_idx[i];
        int e = edge_idx[i];
        if (e >= e_lo && e < e_hi) {
            int pe = atomicAdd(&cur_e[e], 1);
            col_e[pe] = v;              // members (nodes) of each hyperedge
        }
        if (v >= n_lo && v < n_hi) {
            int pn = atomicAdd(&cur_n[v], 1);
            col_n[pn] = e;              // hyperedges incident to each node
        }
    }
}

// ---------------- xw = x @ W  (fp32, BM=64 BN=128 BK=32, 4x8/thread) ----------------
__global__ __launch_bounds__(256) void gemm_kernel(const float* __restrict__ x,
                                                   const float* __restrict__ w,
                                                   float* __restrict__ xw, int nrows) {
    __shared__ float As[64][33];    // [row][k] padded
    __shared__ float Ws[32][128];   // [k][col]
    int tid = threadIdx.x;
    int block_row = blockIdx.x * 64;
    int rg = tid >> 4;              // 0..15
    int cg = tid & 15;              // 0..15
    int r0 = rg * 4, c0 = cg * 8;
    float acc[4][8] = {};
    for (int k0 = 0; k0 < IN_DIM; k0 += 32) {
#pragma unroll
        for (int rep = 0; rep < 2; ++rep) {
            int f = tid + rep * 256;
            int row = f >> 3, kq = f & 7;
            float4 v = make_float4(0.f, 0.f, 0.f, 0.f);
            int grow = block_row + row;
            if (grow < nrows) v = *(const float4*)&x[(size_t)grow * IN_DIM + k0 + kq * 4];
            As[row][kq * 4 + 0] = v.x;
            As[row][kq * 4 + 1] = v.y;
            As[row][kq * 4 + 2] = v.z;
            As[row][kq * 4 + 3] = v.w;
        }
#pragma unroll
        for (int rep = 0; rep < 4; ++rep) {
            int f = tid + rep * 256;
            int kk = f >> 5, cq = f & 31;
            float4 v = *(const float4*)&w[(size_t)(k0 + kk) * OUT_DIM + cq * 4];
            *(float4*)&Ws[kk][cq * 4] = v;
        }
        __syncthreads();
#pragma unroll
        for (int k = 0; k < 32; ++k) {
            float av[4];
#pragma unroll
            for (int i = 0; i < 4; ++i) av[i] = As[r0 + i][k];
            float4 b0 = *(const float4*)&Ws[k][c0];
            float4 b1 = *(const float4*)&Ws[k][c0 + 4];
            float bv[8] = {b0.x, b0.y, b0.z, b0.w, b1.x, b1.y, b1.z, b1.w};
#pragma unroll
            for (int i = 0; i < 4; ++i)
#pragma unroll
                for (int j = 0; j < 8; ++j)
                    acc[i][j] += av[i] * bv[j];
        }
        __syncthreads();
    }
#pragma unroll
    for (int i = 0; i < 4; ++i) {
        int grow = block_row + r0 + i;
        if (grow < nrows) {
            *(float4*)&xw[(size_t)grow * OUT_DIM + c0] =
                make_float4(acc[i][0], acc[i][1], acc[i][2], acc[i][3]);
            *(float4*)&xw[(size_t)grow * OUT_DIM + c0 + 4] =
                make_float4(acc[i][4], acc[i][5], acc[i][6], acc[i][7]);
        }
    }
}

// ---------------- node -> hyperedge aggregation (one wave per edge) ----------------
__global__ __launch_bounds__(256) void edge_agg_kernel(const float* __restrict__ xw,
                                                       const int* __restrict__ rp_e,
                                                       const int* __restrict__ col_e,
                                                       float* __restrict__ m_e) {
    int wave = blockIdx.x * 4 + (threadIdx.x >> 6);
    int lane = threadIdx.x & 63;
    if (wave >= NUM_E) return;
    int beg = rp_e[wave], end = rp_e[wave + 1];
    float2 a0 = make_float2(0.f, 0.f), a1 = make_float2(0.f, 0.f);
    int j = beg;
    for (; j + 2 <= end; j += 2) {
        int n0 = col_e[j], n1 = col_e[j + 1];
        float2 v0 = *(const float2*)&xw[(size_t)n0 * OUT_DIM + lane * 2];
        float2 v1 = *(const float2*)&xw[(size_t)n1 * OUT_DIM + lane * 2];
        a0.x += v0.x; a0.y += v0.y;
        a1.x += v1.x; a1.y += v1.y;
    }
    if (j < end) {
        int n0 = col_e[j];
        float2 v0 = *(const float2*)&xw[(size_t)n0 * OUT_DIM + lane * 2];
        a0.x += v0.x; a0.y += v0.y;
    }
    float binv = (end > beg) ? 1.0f / (float)(end - beg) : 0.0f;
    float2 r = make_float2((a0.x + a1.x) * binv, (a0.y + a1.y) * binv);
    *(float2*)&m_e[(size_t)wave * OUT_DIM + lane * 2] = r;
}

// ---------------- hyperedge -> node + d_inv + bias + relu + mean-pool ----------------
__global__ __launch_bounds__(256) void node_agg_kernel(const float* __restrict__ m_e,
                                                       const int* __restrict__ rp_n,
                                                       const int* __restrict__ col_n,
                                                       const float* __restrict__ bias,
                                                       float* __restrict__ mean_acc) {
    __shared__ float part[128];
    int tid = threadIdx.x;
    if (tid < 128) part[tid] = 0.f;
    __syncthreads();
    int lane = tid & 63;
    int gwave = blockIdx.x * 4 + (tid >> 6);
    int nwaves = gridDim.x * 4;
    float2 b = *(const float2*)&bias[lane * 2];
    float2 macc = make_float2(0.f, 0.f);
    for (int v = gwave; v < NUM_N; v += nwaves) {
        int beg = rp_n[v], end = rp_n[v + 1];
        float2 a0 = make_float2(0.f, 0.f), a1 = make_float2(0.f, 0.f);
        int j = beg;
        for (; j + 2 <= end; j += 2) {
            int e0 = col_n[j], e1 = col_n[j + 1];
            float2 t0 = *(const float2*)&m_e[(size_t)e0 * OUT_DIM + lane * 2];
            float2 t1 = *(const float2*)&m_e[(size_t)e1 * OUT_DIM + lane * 2];
            a0.x += t0.x; a0.y += t0.y;
            a1.x += t1.x; a1.y += t1.y;
        }
        if (j < end) {
            int e0 = col_n[j];
            float2 t0 = *(const float2*)&m_e[(size_t)e0 * OUT_DIM + lane * 2];
            a0.x += t0.x; a0.y += t0.y;
        }
        float dinv = (end > beg) ? 1.0f / (float)(end - beg) : 0.0f;
        float o0 = fmaxf((a0.x + a1.x) * dinv + b.x, 0.f);
        float o1 = fmaxf((a0.y + a1.y) * dinv + b.y, 0.f);
        macc.x += o0; macc.y += o1;
    }
    atomicAdd(&part[lane * 2], macc.x);
    atomicAdd(&part[lane * 2 + 1], macc.y);
    __syncthreads();
    if (tid < 128) atomicAdd(&mean_acc[tid], part[tid]);
}

__global__ void finalize_kernel(const float* __restrict__ mean_acc, float* __restrict__ out) {
    int t = threadIdx.x;
    if (t < 128) out[t] = mean_acc[t] * (1.0f / (float)NUM_N);
}

extern "C" void kernel_launch(void* const* d_in, const int* in_sizes, int n_in,
                              void* d_out, int out_size, void* d_ws, size_t ws_size,
                              hipStream_t stream) {
    const float* x    = (const float*)d_in[0];
    const float* w    = (const float*)d_in[1];
    const float* bias = (const float*)d_in[2];
    const int*   hei  = (const int*)d_in[3];
    int nnz = in_sizes[3] / 2;
    const int* node_idx = hei;        // hyperedge_index[0]
    const int* edge_idx = hei + nnz;  // hyperedge_index[1]
    float* out = (float*)d_out;

    char* ws = (char*)d_ws;
    float* xw   = (float*)(ws);                    // 50000*128*4 = 25,600,000
    float* m_e  = (float*)(ws + 25600000);         // 20000*128*4 = 10,240,000
    int*   col_e = (int*)(ws + 35840000);          // nnz*4 = 6,400,000
    int*   col_n = (int*)(ws + 42240000);          // nnz*4 = 6,400,000
    int*   rp_e  = (int*)(ws + 48640000);          // 20001*4 -> 80,128
    int*   rp_n  = (int*)(ws + 48720128);          // 50001*4 -> 200,192
    int*   cur_e = (int*)(ws + 48920320);          // 20000*4 = 80,000
    int*   cur_n = (int*)(ws + 49000320);          // 50000*4 = 200,000
    int*   cnt_n = (int*)(ws + 49200320);          // 50000*4 = 200,000
    int*   cnt_e = (int*)(ws + 49400320);          // 20000*4 = 80,000
    float* macc  = (float*)(ws + 49480320);        // 128*4   = 512

    // zero counts + mean accumulator (contiguous region)
    hipMemsetAsync(ws + 49200320, 0, 200000 + 80000 + 512, stream);

    hist_kernel<<<2048, 256, 0, stream>>>(node_idx, edge_idx, nnz, cnt_n, cnt_e);
    scan_dual_kernel<<<2, 1024, 0, stream>>>(cnt_e, rp_e, cur_e, cnt_n, rp_n, cur_n);
    fill_part_kernel<<<1024, 256, 0, stream>>>(node_idx, edge_idx, nnz, cur_n, cur_e, col_n, col_e);

    gemm_kernel<<<(NUM_N + 63) / 64, 256, 0, stream>>>(x, w, xw, NUM_N);

    edge_agg_kernel<<<NUM_E / 4, 256, 0, stream>>>(xw, rp_e, col_e, m_e);
    node_agg_kernel<<<1024, 256, 0, stream>>>(m_e, rp_n, col_n, bias, macc);
    finalize_kernel<<<1, 128, 0, stream>>>(macc, out);
}

// Round 3
// 664.489 us; speedup vs baseline: 1.2804x; 1.0826x over previous
//
#include <hip/hip_runtime.h>

#define NUM_N 50000
#define NUM_E 20000
#define IN_DIM 256
#define OUT_DIM 128
#define NPART 8   // one destination range per XCD (blockIdx % 8 round-robins XCDs)

typedef unsigned short ushort_t;
typedef unsigned int uint_t;

// fp32 -> bf16 round-to-nearest-even (values are finite/normal here)
__device__ __forceinline__ ushort_t f2bf(float f) {
    uint_t u = __float_as_uint(f);
    u += 0x7fffu + ((u >> 16) & 1u);
    return (ushort_t)(u >> 16);
}
__device__ __forceinline__ float bf2f(ushort_t b) {
    return __uint_as_float((uint_t)b << 16);
}

// ---------------- histogram: node & edge degrees ----------------
__global__ void hist_kernel(const int* __restrict__ node_idx,
                            const int* __restrict__ edge_idx, int nnz,
                            int* __restrict__ cnt_n, int* __restrict__ cnt_e) {
    int i = blockIdx.x * blockDim.x + threadIdx.x;
    int stride = gridDim.x * blockDim.x;
    for (; i < nnz; i += stride) {
        atomicAdd(&cnt_n[node_idx[i]], 1);
        atomicAdd(&cnt_e[edge_idx[i]], 1);
    }
}

// ---------------- dual single-block exclusive scan -> row_ptr + cur ----------------
__global__ void scan_dual_kernel(const int* __restrict__ cnt_e, int* __restrict__ rp_e,
                                 int* __restrict__ cur_e,
                                 const int* __restrict__ cnt_n, int* __restrict__ rp_n,
                                 int* __restrict__ cur_n) {
    const int* cnt; int* rp; int* cur; int n;
    if (blockIdx.x == 0) { cnt = cnt_e; rp = rp_e; cur = cur_e; n = NUM_E; }
    else                 { cnt = cnt_n; rp = rp_n; cur = cur_n; n = NUM_N; }
    __shared__ int sums[1024];
    int t = threadIdx.x;
    int C = (n + 1023) / 1024;
    int beg = t * C;
    int end = min(beg + C, n);
    int s = 0;
    for (int i = beg; i < end; ++i) s += cnt[i];
    sums[t] = s;
    __syncthreads();
    for (int off = 1; off < 1024; off <<= 1) {
        int v = (t >= off) ? sums[t - off] : 0;
        __syncthreads();
        sums[t] += v;
        __syncthreads();
    }
    int run = (t == 0) ? 0 : sums[t - 1];   // exclusive prefix
    for (int i = beg; i < end; ++i) { rp[i] = run; cur[i] = run; run += cnt[i]; }
    if (t == 1023) rp[n] = run;             // total
}

// ---------------- fill CSR adjacency lists, destination-partitioned ----------------
__global__ __launch_bounds__(256) void fill_part_kernel(const int* __restrict__ node_idx,
                                                        const int* __restrict__ edge_idx, int nnz,
                                                        int* __restrict__ cur_n, int* __restrict__ cur_e,
                                                        int* __restrict__ col_n, int* __restrict__ col_e) {
    int p = blockIdx.x & (NPART - 1);
    int blk = blockIdx.x >> 3;
    int nblk = gridDim.x >> 3;
    const int E_RANGE = NUM_E / NPART;   // 2500
    const int N_RANGE = NUM_N / NPART;   // 6250
    int e_lo = p * E_RANGE, e_hi = e_lo + E_RANGE;
    int n_lo = p * N_RANGE, n_hi = n_lo + N_RANGE;
    int stride = nblk * blockDim.x;
    for (int i = blk * blockDim.x + threadIdx.x; i < nnz; i += stride) {
        int v = node_idx[i];
        int e = edge_idx[i];
        if (e >= e_lo && e < e_hi) {
            int pe = atomicAdd(&cur_e[e], 1);
            col_e[pe] = v;
        }
        if (v >= n_lo && v < n_hi) {
            int pn = atomicAdd(&cur_n[v], 1);
            col_n[pn] = e;
        }
    }
}

// ---------------- xw = x @ W  (fp32 compute, bf16 store) ----------------
__global__ __launch_bounds__(256) void gemm_kernel(const float* __restrict__ x,
                                                   const float* __restrict__ w,
                                                   ushort_t* __restrict__ xw, int nrows) {
    __shared__ float As[64][33];    // [row][k] padded
    __shared__ float Ws[32][128];   // [k][col]
    int tid = threadIdx.x;
    int block_row = blockIdx.x * 64;
    int rg = tid >> 4;              // 0..15
    int cg = tid & 15;              // 0..15
    int r0 = rg * 4, c0 = cg * 8;
    float acc[4][8] = {};
    for (int k0 = 0; k0 < IN_DIM; k0 += 32) {
#pragma unroll
        for (int rep = 0; rep < 2; ++rep) {
            int f = tid + rep * 256;
            int row = f >> 3, kq = f & 7;
            float4 v = make_float4(0.f, 0.f, 0.f, 0.f);
            int grow = block_row + row;
            if (grow < nrows) v = *(const float4*)&x[(size_t)grow * IN_DIM + k0 + kq * 4];
            As[row][kq * 4 + 0] = v.x;
            As[row][kq * 4 + 1] = v.y;
            As[row][kq * 4 + 2] = v.z;
            As[row][kq * 4 + 3] = v.w;
        }
#pragma unroll
        for (int rep = 0; rep < 4; ++rep) {
            int f = tid + rep * 256;
            int kk = f >> 5, cq = f & 31;
            float4 v = *(const float4*)&w[(size_t)(k0 + kk) * OUT_DIM + cq * 4];
            *(float4*)&Ws[kk][cq * 4] = v;
        }
        __syncthreads();
#pragma unroll
        for (int k = 0; k < 32; ++k) {
            float av[4];
#pragma unroll
            for (int i = 0; i < 4; ++i) av[i] = As[r0 + i][k];
            float4 b0 = *(const float4*)&Ws[k][c0];
            float4 b1 = *(const float4*)&Ws[k][c0 + 4];
            float bv[8] = {b0.x, b0.y, b0.z, b0.w, b1.x, b1.y, b1.z, b1.w};
#pragma unroll
            for (int i = 0; i < 4; ++i)
#pragma unroll
                for (int j = 0; j < 8; ++j)
                    acc[i][j] += av[i] * bv[j];
        }
        __syncthreads();
    }
#pragma unroll
    for (int i = 0; i < 4; ++i) {
        int grow = block_row + r0 + i;
        if (grow < nrows) {
            uint4 pk;
            pk.x = (uint_t)f2bf(acc[i][0]) | ((uint_t)f2bf(acc[i][1]) << 16);
            pk.y = (uint_t)f2bf(acc[i][2]) | ((uint_t)f2bf(acc[i][3]) << 16);
            pk.z = (uint_t)f2bf(acc[i][4]) | ((uint_t)f2bf(acc[i][5]) << 16);
            pk.w = (uint_t)f2bf(acc[i][6]) | ((uint_t)f2bf(acc[i][7]) << 16);
            *(uint4*)&xw[(size_t)grow * OUT_DIM + c0] = pk;
        }
    }
}

// ---------------- node -> hyperedge aggregation (one wave per edge, bf16 gather) ----------------
__global__ __launch_bounds__(256) void edge_agg_kernel(const ushort_t* __restrict__ xw,
                                                       const int* __restrict__ rp_e,
                                                       const int* __restrict__ col_e,
                                                       ushort_t* __restrict__ m_e) {
    int wave = blockIdx.x * 4 + (threadIdx.x >> 6);
    int lane = threadIdx.x & 63;
    if (wave >= NUM_E) return;
    int beg = rp_e[wave], end = rp_e[wave + 1];
    float2 a0 = make_float2(0.f, 0.f), a1 = make_float2(0.f, 0.f);
    int j = beg;
    for (; j + 2 <= end; j += 2) {
        int n0 = col_e[j], n1 = col_e[j + 1];
        ushort2 v0 = *(const ushort2*)&xw[(size_t)n0 * OUT_DIM + lane * 2];
        ushort2 v1 = *(const ushort2*)&xw[(size_t)n1 * OUT_DIM + lane * 2];
        a0.x += bf2f(v0.x); a0.y += bf2f(v0.y);
        a1.x += bf2f(v1.x); a1.y += bf2f(v1.y);
    }
    if (j < end) {
        int n0 = col_e[j];
        ushort2 v0 = *(const ushort2*)&xw[(size_t)n0 * OUT_DIM + lane * 2];
        a0.x += bf2f(v0.x); a0.y += bf2f(v0.y);
    }
    float binv = (end > beg) ? 1.0f / (float)(end - beg) : 0.0f;
    ushort2 r;
    r.x = f2bf((a0.x + a1.x) * binv);
    r.y = f2bf((a0.y + a1.y) * binv);
    *(ushort2*)&m_e[(size_t)wave * OUT_DIM + lane * 2] = r;
}

// ---------------- hyperedge -> node + d_inv + bias + relu + mean-pool ----------------
__global__ __launch_bounds__(256) void node_agg_kernel(const ushort_t* __restrict__ m_e,
                                                       const int* __restrict__ rp_n,
                                                       const int* __restrict__ col_n,
                                                       const float* __restrict__ bias,
                                                       float* __restrict__ mean_acc) {
    __shared__ float part[128];
    int tid = threadIdx.x;
    if (tid < 128) part[tid] = 0.f;
    __syncthreads();
    int lane = tid & 63;
    int gwave = blockIdx.x * 4 + (tid >> 6);
    int nwaves = gridDim.x * 4;
    float2 b = *(const float2*)&bias[lane * 2];
    float2 macc = make_float2(0.f, 0.f);
    for (int v = gwave; v < NUM_N; v += nwaves) {
        int beg = rp_n[v], end = rp_n[v + 1];
        float2 a0 = make_float2(0.f, 0.f), a1 = make_float2(0.f, 0.f);
        int j = beg;
        for (; j + 2 <= end; j += 2) {
            int e0 = col_n[j], e1 = col_n[j + 1];
            ushort2 t0 = *(const ushort2*)&m_e[(size_t)e0 * OUT_DIM + lane * 2];
            ushort2 t1 = *(const ushort2*)&m_e[(size_t)e1 * OUT_DIM + lane * 2];
            a0.x += bf2f(t0.x); a0.y += bf2f(t0.y);
            a1.x += bf2f(t1.x); a1.y += bf2f(t1.y);
        }
        if (j < end) {
            int e0 = col_n[j];
            ushort2 t0 = *(const ushort2*)&m_e[(size_t)e0 * OUT_DIM + lane * 2];
            a0.x += bf2f(t0.x); a0.y += bf2f(t0.y);
        }
        float dinv = (end > beg) ? 1.0f / (float)(end - beg) : 0.0f;
        float o0 = fmaxf((a0.x + a1.x) * dinv + b.x, 0.f);
        float o1 = fmaxf((a0.y + a1.y) * dinv + b.y, 0.f);
        macc.x += o0; macc.y += o1;
    }
    atomicAdd(&part[lane * 2], macc.x);
    atomicAdd(&part[lane * 2 + 1], macc.y);
    __syncthreads();
    if (tid < 128) atomicAdd(&mean_acc[tid], part[tid]);
}

__global__ void finalize_kernel(const float* __restrict__ mean_acc, float* __restrict__ out) {
    int t = threadIdx.x;
    if (t < 128) out[t] = mean_acc[t] * (1.0f / (float)NUM_N);
}

extern "C" void kernel_launch(void* const* d_in, const int* in_sizes, int n_in,
                              void* d_out, int out_size, void* d_ws, size_t ws_size,
                              hipStream_t stream) {
    const float* x    = (const float*)d_in[0];
    const float* w    = (const float*)d_in[1];
    const float* bias = (const float*)d_in[2];
    const int*   hei  = (const int*)d_in[3];
    int nnz = in_sizes[3] / 2;
    const int* node_idx = hei;        // hyperedge_index[0]
    const int* edge_idx = hei + nnz;  // hyperedge_index[1]
    float* out = (float*)d_out;

    char* ws = (char*)d_ws;
    ushort_t* xw   = (ushort_t*)(ws);              // 50000*128*2 = 12,800,000
    ushort_t* m_e  = (ushort_t*)(ws + 12800000);   // 20000*128*2 =  5,120,000
    int*   col_e = (int*)(ws + 17920000);          // nnz*4 = 6,400,000
    int*   col_n = (int*)(ws + 24320000);          // nnz*4 = 6,400,000
    int*   rp_e  = (int*)(ws + 30720000);          // 20001*4
    int*   rp_n  = (int*)(ws + 30800128);          // 50001*4
    int*   cur_e = (int*)(ws + 31000320);          // 20000*4
    int*   cur_n = (int*)(ws + 31080320);          // 50000*4
    int*   cnt_n = (int*)(ws + 31280320);          // 50000*4
    int*   cnt_e = (int*)(ws + 31480320);          // 20000*4
    float* macc  = (float*)(ws + 31560320);        // 128*4

    // zero counts + mean accumulator (contiguous region)
    hipMemsetAsync(ws + 31280320, 0, 200000 + 80000 + 512, stream);

    hist_kernel<<<2048, 256, 0, stream>>>(node_idx, edge_idx, nnz, cnt_n, cnt_e);
    scan_dual_kernel<<<2, 1024, 0, stream>>>(cnt_e, rp_e, cur_e, cnt_n, rp_n, cur_n);
    fill_part_kernel<<<1024, 256, 0, stream>>>(node_idx, edge_idx, nnz, cur_n, cur_e, col_n, col_e);

    gemm_kernel<<<(NUM_N + 63) / 64, 256, 0, stream>>>(x, w, xw, NUM_N);

    edge_agg_kernel<<<NUM_E / 4, 256, 0, stream>>>(xw, rp_e, col_e, m_e);
    node_agg_kernel<<<2048, 256, 0, stream>>>(m_e, rp_n, col_n, bias, macc);
    finalize_kernel<<<1, 128, 0, stream>>>(macc, out);
}

// Round 4
// 569.727 us; speedup vs baseline: 1.4934x; 1.1663x over previous
//
#include <hip/hip_runtime.h>

#define NUM_N 50000
#define NUM_E 20000
#define IN_DIM 256
#define OUT_DIM 128
#define NPART 8        // one destination range per XCD (blockIdx % 8 round-robins XCDs)
#define HIST_K 64      // blocks per partition in histogram
#define HN (NUM_N / NPART)   // 6250
#define HE (NUM_E / NPART)   // 2500

typedef unsigned short ushort_t;
typedef unsigned int uint_t;

// fp32 -> bf16 round-to-nearest-even
__device__ __forceinline__ ushort_t f2bf(float f) {
    uint_t u = __float_as_uint(f);
    u += 0x7fffu + ((u >> 16) & 1u);
    return (ushort_t)(u >> 16);
}
__device__ __forceinline__ float bf_lo(uint_t v) { return __uint_as_float(v << 16); }
__device__ __forceinline__ float bf_hi(uint_t v) { return __uint_as_float(v & 0xffff0000u); }

// ---------------- LDS-partitioned histogram: node & edge degrees ----------------
// Partition p = blockIdx & 7 owns node range [p*HN,(p+1)*HN) and edge range
// [p*HE,(p+1)*HE). Bins live in LDS; one global atomicAdd per nonzero bin at
// the end. All of partition p's blocks share blockIdx%8 == p -> same XCD ->
// flush lines merge in that XCD's L2 (no cross-XCD line bouncing).
__global__ __launch_bounds__(256) void hist_lds_kernel(const int* __restrict__ node_idx,
                                                       const int* __restrict__ edge_idx, int nnz,
                                                       int* __restrict__ cnt_n, int* __restrict__ cnt_e) {
    __shared__ int bins_n[HN];
    __shared__ int bins_e[HE];
    int tid = threadIdx.x;
    int p = blockIdx.x & (NPART - 1);
    int blk = blockIdx.x >> 3;
    int nblk = gridDim.x >> 3;
    for (int i = tid; i < HN; i += 256) bins_n[i] = 0;
    for (int i = tid; i < HE; i += 256) bins_e[i] = 0;
    __syncthreads();
    int n_lo = p * HN, n_hi = n_lo + HN;
    int e_lo = p * HE, e_hi = e_lo + HE;
    int stride = nblk * 256;
    for (int i = blk * 256 + tid; i < nnz; i += stride) {
        int v = node_idx[i];
        int e = edge_idx[i];
        if (v >= n_lo && v < n_hi) atomicAdd(&bins_n[v - n_lo], 1);
        if (e >= e_lo && e < e_hi) atomicAdd(&bins_e[e - e_lo], 1);
    }
    __syncthreads();
    for (int i = tid; i < HN; i += 256) {
        int c = bins_n[i];
        if (c) atomicAdd(&cnt_n[n_lo + i], c);
    }
    for (int i = tid; i < HE; i += 256) {
        int c = bins_e[i];
        if (c) atomicAdd(&cnt_e[e_lo + i], c);
    }
}

// ---------------- dual single-block exclusive scan -> row_ptr + cur ----------------
__global__ void scan_dual_kernel(const int* __restrict__ cnt_e, int* __restrict__ rp_e,
                                 int* __restrict__ cur_e,
                                 const int* __restrict__ cnt_n, int* __restrict__ rp_n,
                                 int* __restrict__ cur_n) {
    const int* cnt; int* rp; int* cur; int n;
    if (blockIdx.x == 0) { cnt = cnt_e; rp = rp_e; cur = cur_e; n = NUM_E; }
    else                 { cnt = cnt_n; rp = rp_n; cur = cur_n; n = NUM_N; }
    __shared__ int sums[1024];
    int t = threadIdx.x;
    int C = (n + 1023) / 1024;
    int beg = t * C;
    int end = min(beg + C, n);
    int s = 0;
    for (int i = beg; i < end; ++i) s += cnt[i];
    sums[t] = s;
    __syncthreads();
    for (int off = 1; off < 1024; off <<= 1) {
        int v = (t >= off) ? sums[t - off] : 0;
        __syncthreads();
        sums[t] += v;
        __syncthreads();
    }
    int run = (t == 0) ? 0 : sums[t - 1];   // exclusive prefix
    for (int i = beg; i < end; ++i) { rp[i] = run; cur[i] = run; run += cnt[i]; }
    if (t == 1023) rp[n] = run;             // total
}

// ---------------- fill CSR adjacency lists, destination-partitioned ----------------
__global__ __launch_bounds__(256) void fill_part_kernel(const int* __restrict__ node_idx,
                                                        const int* __restrict__ edge_idx, int nnz,
                                                        int* __restrict__ cur_n, int* __restrict__ cur_e,
                                                        int* __restrict__ col_n, int* __restrict__ col_e) {
    int p = blockIdx.x & (NPART - 1);
    int blk = blockIdx.x >> 3;
    int nblk = gridDim.x >> 3;
    int e_lo = p * HE, e_hi = e_lo + HE;
    int n_lo = p * HN, n_hi = n_lo + HN;
    int stride = nblk * blockDim.x;
    for (int i = blk * blockDim.x + threadIdx.x; i < nnz; i += stride) {
        int v = node_idx[i];
        int e = edge_idx[i];
        if (e >= e_lo && e < e_hi) {
            int pe = atomicAdd(&cur_e[e], 1);
            col_e[pe] = v;
        }
        if (v >= n_lo && v < n_hi) {
            int pn = atomicAdd(&cur_n[v], 1);
            col_n[pn] = e;
        }
    }
}

// ---------------- xw = x @ W  (fp32 compute, bf16 store) ----------------
__global__ __launch_bounds__(256) void gemm_kernel(const float* __restrict__ x,
                                                   const float* __restrict__ w,
                                                   ushort_t* __restrict__ xw, int nrows) {
    __shared__ float As[64][33];    // [row][k] padded
    __shared__ float Ws[32][128];   // [k][col]
    int tid = threadIdx.x;
    int block_row = blockIdx.x * 64;
    int rg = tid >> 4;              // 0..15
    int cg = tid & 15;              // 0..15
    int r0 = rg * 4, c0 = cg * 8;
    float acc[4][8] = {};
    for (int k0 = 0; k0 < IN_DIM; k0 += 32) {
#pragma unroll
        for (int rep = 0; rep < 2; ++rep) {
            int f = tid + rep * 256;
            int row = f >> 3, kq = f & 7;
            float4 v = make_float4(0.f, 0.f, 0.f, 0.f);
            int grow = block_row + row;
            if (grow < nrows) v = *(const float4*)&x[(size_t)grow * IN_DIM + k0 + kq * 4];
            As[row][kq * 4 + 0] = v.x;
            As[row][kq * 4 + 1] = v.y;
            As[row][kq * 4 + 2] = v.z;
            As[row][kq * 4 + 3] = v.w;
        }
#pragma unroll
        for (int rep = 0; rep < 4; ++rep) {
            int f = tid + rep * 256;
            int kk = f >> 5, cq = f & 31;
            float4 v = *(const float4*)&w[(size_t)(k0 + kk) * OUT_DIM + cq * 4];
            *(float4*)&Ws[kk][cq * 4] = v;
        }
        __syncthreads();
#pragma unroll
        for (int k = 0; k < 32; ++k) {
            float av[4];
#pragma unroll
            for (int i = 0; i < 4; ++i) av[i] = As[r0 + i][k];
            float4 b0 = *(const float4*)&Ws[k][c0];
            float4 b1 = *(const float4*)&Ws[k][c0 + 4];
            float bv[8] = {b0.x, b0.y, b0.z, b0.w, b1.x, b1.y, b1.z, b1.w};
#pragma unroll
            for (int i = 0; i < 4; ++i)
#pragma unroll
                for (int j = 0; j < 8; ++j)
                    acc[i][j] += av[i] * bv[j];
        }
        __syncthreads();
    }
#pragma unroll
    for (int i = 0; i < 4; ++i) {
        int grow = block_row + r0 + i;
        if (grow < nrows) {
            uint4 pk;
            pk.x = (uint_t)f2bf(acc[i][0]) | ((uint_t)f2bf(acc[i][1]) << 16);
            pk.y = (uint_t)f2bf(acc[i][2]) | ((uint_t)f2bf(acc[i][3]) << 16);
            pk.z = (uint_t)f2bf(acc[i][4]) | ((uint_t)f2bf(acc[i][5]) << 16);
            pk.w = (uint_t)f2bf(acc[i][6]) | ((uint_t)f2bf(acc[i][7]) << 16);
            *(uint4*)&xw[(size_t)grow * OUT_DIM + c0] = pk;
        }
    }
}

// ---------------- node -> hyperedge aggregation ----------------
// Half-wave per row: lanes 0-31 row j, lanes 32-63 row j+1; each lane loads
// uint2 = 4 bf16 (8 B). Halves combined with shfl_xor(32).
__global__ __launch_bounds__(256) void edge_agg_kernel(const ushort_t* __restrict__ xw,
                                                       const int* __restrict__ rp_e,
                                                       const int* __restrict__ col_e,
                                                       ushort_t* __restrict__ m_e) {
    int wave = blockIdx.x * 4 + (threadIdx.x >> 6);
    int lane = threadIdx.x & 63;
    if (wave >= NUM_E) return;
    int half = lane >> 5;       // 0 or 1
    int sub = lane & 31;        // column group: cols sub*4 .. sub*4+3
    int beg = rp_e[wave], end = rp_e[wave + 1];
    float a0 = 0.f, a1 = 0.f, a2 = 0.f, a3 = 0.f;
    for (int j = beg + half; j < end; j += 2) {
        int n = col_e[j];
        uint2 v = *(const uint2*)&xw[(size_t)n * OUT_DIM + sub * 4];
        a0 += bf_lo(v.x); a1 += bf_hi(v.x);
        a2 += bf_lo(v.y); a3 += bf_hi(v.y);
    }
    a0 += __shfl_xor(a0, 32, 64);
    a1 += __shfl_xor(a1, 32, 64);
    a2 += __shfl_xor(a2, 32, 64);
    a3 += __shfl_xor(a3, 32, 64);
    if (half == 0) {
        float binv = (end > beg) ? 1.0f / (float)(end - beg) : 0.0f;
        uint2 pk;
        pk.x = (uint_t)f2bf(a0 * binv) | ((uint_t)f2bf(a1 * binv) << 16);
        pk.y = (uint_t)f2bf(a2 * binv) | ((uint_t)f2bf(a3 * binv) << 16);
        *(uint2*)&m_e[(size_t)wave * OUT_DIM + sub * 4] = pk;
    }
}

// ---------------- hyperedge -> node + d_inv + bias + relu + mean-pool ----------------
__global__ __launch_bounds__(256) void node_agg_kernel(const ushort_t* __restrict__ m_e,
                                                       const int* __restrict__ rp_n,
                                                       const int* __restrict__ col_n,
                                                       const float* __restrict__ bias,
                                                       float* __restrict__ mean_acc) {
    __shared__ float part[128];
    int tid = threadIdx.x;
    if (tid < 128) part[tid] = 0.f;
    __syncthreads();
    int lane = tid & 63;
    int half = lane >> 5;
    int sub = lane & 31;
    int gwave = blockIdx.x * 4 + (tid >> 6);
    int nwaves = gridDim.x * 4;
    float4 b = *(const float4*)&bias[sub * 4];
    float m0 = 0.f, m1 = 0.f, m2 = 0.f, m3 = 0.f;
    for (int v = gwave; v < NUM_N; v += nwaves) {
        int beg = rp_n[v], end = rp_n[v + 1];
        float a0 = 0.f, a1 = 0.f, a2 = 0.f, a3 = 0.f;
        for (int j = beg + half; j < end; j += 2) {
            int e = col_n[j];
            uint2 t = *(const uint2*)&m_e[(size_t)e * OUT_DIM + sub * 4];
            a0 += bf_lo(t.x); a1 += bf_hi(t.x);
            a2 += bf_lo(t.y); a3 += bf_hi(t.y);
        }
        a0 += __shfl_xor(a0, 32, 64);
        a1 += __shfl_xor(a1, 32, 64);
        a2 += __shfl_xor(a2, 32, 64);
        a3 += __shfl_xor(a3, 32, 64);
        if (half == 0) {
            float dinv = (end > beg) ? 1.0f / (float)(end - beg) : 0.0f;
            m0 += fmaxf(a0 * dinv + b.x, 0.f);
            m1 += fmaxf(a1 * dinv + b.y, 0.f);
            m2 += fmaxf(a2 * dinv + b.z, 0.f);
            m3 += fmaxf(a3 * dinv + b.w, 0.f);
        }
    }
    if (half == 0) {
        atomicAdd(&part[sub * 4 + 0], m0);
        atomicAdd(&part[sub * 4 + 1], m1);
        atomicAdd(&part[sub * 4 + 2], m2);
        atomicAdd(&part[sub * 4 + 3], m3);
    }
    __syncthreads();
    if (tid < 128) atomicAdd(&mean_acc[tid], part[tid]);
}

__global__ void finalize_kernel(const float* __restrict__ mean_acc, float* __restrict__ out) {
    int t = threadIdx.x;
    if (t < 128) out[t] = mean_acc[t] * (1.0f / (float)NUM_N);
}

extern "C" void kernel_launch(void* const* d_in, const int* in_sizes, int n_in,
                              void* d_out, int out_size, void* d_ws, size_t ws_size,
                              hipStream_t stream) {
    const float* x    = (const float*)d_in[0];
    const float* w    = (const float*)d_in[1];
    const float* bias = (const float*)d_in[2];
    const int*   hei  = (const int*)d_in[3];
    int nnz = in_sizes[3] / 2;
    const int* node_idx = hei;        // hyperedge_index[0]
    const int* edge_idx = hei + nnz;  // hyperedge_index[1]
    float* out = (float*)d_out;

    char* ws = (char*)d_ws;
    ushort_t* xw   = (ushort_t*)(ws);              // 50000*128*2 = 12,800,000
    ushort_t* m_e  = (ushort_t*)(ws + 12800000);   // 20000*128*2 =  5,120,000
    int*   col_e = (int*)(ws + 17920000);          // nnz*4 = 6,400,000
    int*   col_n = (int*)(ws + 24320000);          // nnz*4 = 6,400,000
    int*   rp_e  = (int*)(ws + 30720000);          // 20001*4
    int*   rp_n  = (int*)(ws + 30800128);          // 50001*4
    int*   cur_e = (int*)(ws + 31000320);          // 20000*4
    int*   cur_n = (int*)(ws + 31080320);          // 50000*4
    int*   cnt_n = (int*)(ws + 31280320);          // 50000*4
    int*   cnt_e = (int*)(ws + 31480320);          // 20000*4
    float* macc  = (float*)(ws + 31560320);        // 128*4

    // zero counts + mean accumulator (contiguous region)
    hipMemsetAsync(ws + 31280320, 0, 200000 + 80000 + 512, stream);

    hist_lds_kernel<<<NPART * HIST_K, 256, 0, stream>>>(node_idx, edge_idx, nnz, cnt_n, cnt_e);
    scan_dual_kernel<<<2, 1024, 0, stream>>>(cnt_e, rp_e, cur_e, cnt_n, rp_n, cur_n);
    fill_part_kernel<<<1024, 256, 0, stream>>>(node_idx, edge_idx, nnz, cur_n, cur_e, col_n, col_e);

    gemm_kernel<<<(NUM_N + 63) / 64, 256, 0, stream>>>(x, w, xw, NUM_N);

    edge_agg_kernel<<<NUM_E / 4, 256, 0, stream>>>(xw, rp_e, col_e, m_e);
    node_agg_kernel<<<2048, 256, 0, stream>>>(m_e, rp_n, col_n, bias, macc);
    finalize_kernel<<<1, 128, 0, stream>>>(macc, out);
}